// Round 13
// baseline (320.238 us; speedup 1.0000x reference)
//
#include <hip/hip_runtime.h>
#include <stdint.h>

typedef unsigned short ushort_t;
typedef __attribute__((ext_vector_type(8))) short s16x8;
typedef __attribute__((ext_vector_type(8))) unsigned short u16x8;
typedef __attribute__((ext_vector_type(4))) unsigned short u16x4;
typedef __attribute__((ext_vector_type(4))) float f32x4;

#define AS1C(p) ((const __attribute__((address_space(1))) void*)(p))
#define AS3(p)  ((__attribute__((address_space(3))) void*)(p))

// 0.5 (attention scale) * log2(e)  — baked into Wq/bq so softmax can use exp2
#define QSCALE 0.7213475204444817f

// hardware exp2 / log2 (v_exp_f32 = 2^x, v_log_f32 = log2 x)
#define EXP2F(x) __builtin_amdgcn_exp2f(x)
#define LOG2F(x) __builtin_amdgcn_logf(x)

// per-wave LDS fence: own-wave ds op ordering without s_barrier
#define WAVE_LDS_FENCE()                                    \
  do {                                                      \
    asm volatile("s_waitcnt lgkmcnt(0)" ::: "memory");      \
    __builtin_amdgcn_sched_barrier(0);                      \
  } while (0)

// raw workgroup barrier, compiler-fenced on both sides (waits done explicitly)
#define SBAR()                                              \
  do {                                                      \
    __builtin_amdgcn_sched_barrier(0);                      \
    __builtin_amdgcn_s_barrier();                           \
    __builtin_amdgcn_sched_barrier(0);                      \
  } while (0)

__device__ __forceinline__ ushort_t f2bf(float f) {
  uint32_t u = __float_as_uint(f);
  u += 0x7fffu + ((u >> 16) & 1u);
  return (ushort_t)(u >> 16);
}
__device__ __forceinline__ float bf2f(ushort_t h) {
  return __uint_as_float(((uint32_t)h) << 16);
}

// ---------------- activations f32 -> bf16 (3 tensors, one launch) ----------------
__global__ __launch_bounds__(256) void cvt3_kernel(const float* __restrict__ s0,
                                                   const float* __restrict__ s1,
                                                   const float* __restrict__ s2,
                                                   ushort_t* __restrict__ dst) {
  const int y = blockIdx.y;
  const float* src = y == 0 ? s0 : (y == 1 ? s1 : s2);
  const int i = blockIdx.x * 256 + threadIdx.x;
  const float4 v = ((const float4*)src)[i];
  ushort4 o;
  o.x = f2bf(v.x); o.y = f2bf(v.y); o.z = f2bf(v.z); o.w = f2bf(v.w);
  ((ushort4*)(dst + (size_t)y * 8388608))[i] = o;
}

// ---------------- weights f32 -> bf16 (Wq scaled by QSCALE), one launch ----------------
__global__ __launch_bounds__(256) void cvtw_kernel(const float* __restrict__ w0,
                                                   const float* __restrict__ w1,
                                                   const float* __restrict__ w2,
                                                   const float* __restrict__ w3,
                                                   ushort_t* __restrict__ dqkv,
                                                   ushort_t* __restrict__ dwo) {
  const int y = blockIdx.y;
  const float* src = y == 0 ? w0 : (y == 1 ? w1 : (y == 2 ? w2 : w3));
  ushort_t* dst = y < 3 ? dqkv + (size_t)y * 1048576 : dwo;
  const float sc = y == 0 ? QSCALE : 1.0f;
  const int i = blockIdx.x * 256 + threadIdx.x;
  const float4 v = ((const float4*)src)[i];
  ushort4 o;
  o.x = f2bf(v.x * sc); o.y = f2bf(v.y * sc); o.z = f2bf(v.z * sc); o.w = f2bf(v.w * sc);
  ((ushort4*)dst)[i] = o;
}

// ---------------- concat bias (bq scaled) ----------------
__global__ __launch_bounds__(256) void biascat_kernel(const float* __restrict__ bq,
                                                      const float* __restrict__ bk,
                                                      const float* __restrict__ bv,
                                                      float* __restrict__ dst) {
  const int i = blockIdx.x * 256 + threadIdx.x;
  dst[i] = i < 1024 ? bq[i] * QSCALE : (i < 2048 ? bk[i - 1024] : bv[i - 2048]);
}

// ---------------- bf16 NT GEMM, 128x128 tile, BK=32, 3-buffer ring ----------------
// 512 threads / 8 waves (4 M-waves x 2 N-waves; 32x64 per wave, acc[2][4]).
// ADD_RESID: epilogue adds resid[m][n] (residual fused into out-proj).
template <int OUT_BF16, int ADD_RESID>
__global__ __launch_bounds__(512) void gemm_nt(const ushort_t* __restrict__ A0,
                                               const ushort_t* __restrict__ A1,
                                               const ushort_t* __restrict__ A2,
                                               const ushort_t* __restrict__ B,
                                               const float* __restrict__ bias,
                                               const float* __restrict__ resid,
                                               void* __restrict__ C0,
                                               void* __restrict__ C1,
                                               void* __restrict__ C2) {
  __shared__ ushort_t As[3][128 * 32];
  __shared__ ushort_t Bs[3][128 * 32];
  const int tid = threadIdx.x;
  const int w = tid >> 6, lane = tid & 63, g = lane >> 4, c = lane & 15;
  const int wm = w >> 1, wn = w & 1;   // 4 M-waves x 2 N-waves
  const int m0 = blockIdx.y * 128, n0 = blockIdx.x * 128;
  const int sel = n0 >> 10, nloc0 = n0 & 1023;
  const ushort_t* A = sel == 0 ? A0 : (sel == 1 ? A1 : A2);
  char* C = (char*)(sel == 0 ? C0 : (sel == 1 ? C1 : C2));
  f32x4 acc[2][4] = {};

  const int srow = tid >> 2, scol = (tid & 3) << 3;
  const int sdst = (w * 64) * 8;  // wave-uniform base (elems)

#define G_STAGE(buf, k0_)                                                                  \
  do {                                                                                     \
    __builtin_amdgcn_global_load_lds(AS1C(&A[(size_t)(m0 + srow) * 1024 + (k0_) + scol]),  \
                                     AS3(&As[buf][sdst]), 16, 0, 0);                       \
    __builtin_amdgcn_global_load_lds(AS1C(&B[(size_t)(n0 + srow) * 1024 + (k0_) + scol]),  \
                                     AS3(&Bs[buf][sdst]), 16, 0, 0);                       \
  } while (0)

  G_STAGE(0, 0);
  G_STAGE(1, 32);
  asm volatile("s_waitcnt vmcnt(2)" ::: "memory");
  SBAR();
  int cur = 0;
  for (int it = 0; it < 32; ++it) {
    if (it < 30) {
      const int sb = cur >= 1 ? cur - 1 : 2;  // (cur+2)%3
      G_STAGE(sb, 32 * (it + 2));
    }
    s16x8 af[2], bfr[4];
#pragma unroll
    for (int mi = 0; mi < 2; ++mi)
      af[mi] = *(const s16x8*)&As[cur][(wm * 32 + mi * 16 + c) * 32 + g * 8];
#pragma unroll
    for (int ni = 0; ni < 4; ++ni)
      bfr[ni] = *(const s16x8*)&Bs[cur][(wn * 64 + ni * 16 + c) * 32 + g * 8];
    __builtin_amdgcn_s_setprio(1);
#pragma unroll
    for (int mi = 0; mi < 2; ++mi)
#pragma unroll
      for (int ni = 0; ni < 4; ++ni)
        acc[mi][ni] = __builtin_amdgcn_mfma_f32_16x16x32_bf16(af[mi], bfr[ni], acc[mi][ni], 0, 0, 0);
    __builtin_amdgcn_s_setprio(0);
    if (it < 31) {
      if (it < 30)
        asm volatile("s_waitcnt vmcnt(2) lgkmcnt(0)" ::: "memory");
      else
        asm volatile("s_waitcnt vmcnt(0) lgkmcnt(0)" ::: "memory");
      SBAR();
    }
    cur = cur < 2 ? cur + 1 : 0;
  }
#undef G_STAGE

#pragma unroll
  for (int ni = 0; ni < 4; ++ni) {
    const int nn = wn * 64 + ni * 16 + c;
    const float bv = bias[n0 + nn];
#pragma unroll
    for (int mi = 0; mi < 2; ++mi) {
#pragma unroll
      for (int rr = 0; rr < 4; ++rr) {
        const int m = m0 + wm * 32 + mi * 16 + g * 4 + rr;
        float val = acc[mi][ni][rr] + bv;
        if (ADD_RESID) val += resid[(size_t)m * 1024 + nloc0 + nn];
        if (OUT_BF16)
          ((ushort_t*)C)[(size_t)m * 1024 + nloc0 + nn] = f2bf(val);
        else
          ((float*)C)[(size_t)m * 1024 + nloc0 + nn] = val;
      }
    }
  }
}

// ---------------- V transpose per head: vt[n][dh][i] = v[n][i][dh] ----------------
__global__ __launch_bounds__(256) void transpose_v(const ushort_t* __restrict__ v,
                                                   ushort_t* __restrict__ vt) {
  __shared__ ushort_t T[64][72];
  const int n = blockIdx.y, ib = blockIdx.x;
  const int t = threadIdx.x;
  {
    const int row = t >> 2, cb = (t & 3) << 4;
    const ushort_t* src = v + (size_t)n * 65536 + (size_t)(ib * 64 + row) * 64 + cb;
    *(u16x8*)&T[row][cb] = *(const u16x8*)src;
    *(u16x8*)&T[row][cb + 8] = *(const u16x8*)(src + 8);
  }
  __syncthreads();
  {
    const int dh = t >> 2, ibs = (t & 3) << 4;
    u16x8 a, b;
#pragma unroll
    for (int e = 0; e < 8; ++e) { a[e] = T[ibs + e][dh]; b[e] = T[ibs + 8 + e][dh]; }
    ushort_t* dst = vt + (size_t)n * 65536 + (size_t)dh * 1024 + ib * 64 + ibs;
    *(u16x8*)dst = a;
    *(u16x8*)(dst + 8) = b;
  }
}

// ---------------- softmax stats: bias[row] = log2( sum_j exp2(S[row][j]) ) ----------------
// 256 q-rows per block (4 waves x 64 rows, 4 fragments each); 3-buffer ring, vmcnt(2).
__global__ __launch_bounds__(256) void stats_kernel(const ushort_t* __restrict__ q,
                                                    const ushort_t* __restrict__ k,
                                                    float* __restrict__ bias_out) {
  __shared__ ushort_t Kb[3][64 * 64];
  const int wg = blockIdx.x;
  const int idx = ((wg & 7) << 6) | (wg >> 3);  // XCD swizzle (bijective, 512=8*64)
  const int n = idx >> 2, qb = idx & 3;
  const int tid = threadIdx.x, w = tid >> 6, lane = tid & 63, g = lane >> 4, c = lane & 15;
  const int q0 = qb * 256 + w * 64;
  const ushort_t* qh = q + (size_t)n * 65536;
  const char* khb = (const char*)(k + (size_t)n * 65536);

  const int r0 = w * 16 + (lane >> 3);
  const int csw = (((lane & 7) ^ (lane >> 3)) << 4);

#define STAGE_KS(buf, jt_)                                                                  \
  do {                                                                                      \
    __builtin_amdgcn_global_load_lds(AS1C(khb + ((size_t)(jt_)*64 + r0) * 128 + csw),       \
                                     AS3(&Kb[buf][(w * 2 + 0) * 512]), 16, 0, 0);           \
    __builtin_amdgcn_global_load_lds(AS1C(khb + ((size_t)(jt_)*64 + r0 + 8) * 128 + csw),   \
                                     AS3(&Kb[buf][(w * 2 + 1) * 512]), 16, 0, 0);           \
  } while (0)
#define KFRAGS(buf, jn, h)                                                    \
  (*(const s16x8*)((const char*)&Kb[buf][0] +                                 \
                   (((((jn)*16 + c) * 128 + (h)*64 + g * 16)) ^ ((c & 7) << 4))))

  s16x8 aq[4][2];
#pragma unroll
  for (int fr = 0; fr < 4; ++fr) {
    aq[fr][0] = *(const s16x8*)&qh[(q0 + fr * 16 + c) * 64 + g * 8];
    aq[fr][1] = *(const s16x8*)&qh[(q0 + fr * 16 + c) * 64 + 32 + g * 8];
  }

  float l_acc[4][4] = {};

  STAGE_KS(0, 0);
  STAGE_KS(1, 1);
  asm volatile("s_waitcnt vmcnt(2)" ::: "memory");
  SBAR();
  int cur = 0;
  for (int jt = 0; jt < 16; ++jt) {
    if (jt < 14) {
      const int sb = cur >= 1 ? cur - 1 : 2;  // (cur+2)%3
      STAGE_KS(sb, jt + 2);
    }
#pragma unroll
    for (int fr = 0; fr < 4; ++fr) {
      f32x4 sfr[4];
      __builtin_amdgcn_s_setprio(1);
#pragma unroll
      for (int jn = 0; jn < 4; ++jn) {
        f32x4 z = {0.f, 0.f, 0.f, 0.f};
        z = __builtin_amdgcn_mfma_f32_16x16x32_bf16(aq[fr][0], KFRAGS(cur, jn, 0), z, 0, 0, 0);
        z = __builtin_amdgcn_mfma_f32_16x16x32_bf16(aq[fr][1], KFRAGS(cur, jn, 1), z, 0, 0, 0);
        sfr[jn] = z;
      }
      __builtin_amdgcn_s_setprio(0);
#pragma unroll
      for (int rr = 0; rr < 4; ++rr)
        l_acc[fr][rr] += EXP2F(sfr[0][rr]) + EXP2F(sfr[1][rr]) +
                         EXP2F(sfr[2][rr]) + EXP2F(sfr[3][rr]);
    }
    if (jt < 15) {
      if (jt < 14)
        asm volatile("s_waitcnt vmcnt(2) lgkmcnt(0)" ::: "memory");
      else
        asm volatile("s_waitcnt vmcnt(0) lgkmcnt(0)" ::: "memory");
      SBAR();
    }
    cur = cur < 2 ? cur + 1 : 0;
  }

#pragma unroll
  for (int fr = 0; fr < 4; ++fr)
#pragma unroll
    for (int rr = 0; rr < 4; ++rr) {
      float l = l_acc[fr][rr];
      l += __shfl_xor(l, 1);
      l += __shfl_xor(l, 2);
      l += __shfl_xor(l, 4);
      l += __shfl_xor(l, 8);
      if (c == 0)
        bias_out[(size_t)n * 1024 + q0 + fr * 16 + g * 4 + rr] = LOG2F(l);
    }
#undef STAGE_KS
#undef KFRAGS
}

// ---------------- attention: single sweep, 128 q-rows per block (R10 exact) ----------------
// 4 waves x 32 rows (2 fragments each): K/V staged once per 128 rows, V-frags
// reused across fragments, barriers halved per row. Nontemporal f32 P stores.
__global__ __launch_bounds__(256) void attn_kernel(const ushort_t* __restrict__ q,
                                                   const ushort_t* __restrict__ k,
                                                   const ushort_t* __restrict__ vt,
                                                   const float* __restrict__ stats,
                                                   float* __restrict__ attn,
                                                   ushort_t* __restrict__ ctx) {
  __shared__ ushort_t Kb[2][64 * 64];
  __shared__ ushort_t Vb[2][64 * 64];
  __shared__ ushort_t Pb[4][32 * 64];
  const int wg = blockIdx.x;
  const int idx = ((wg & 7) << 7) | (wg >> 3);  // XCD swizzle (bijective, 1024=8*128)
  const int n = idx >> 3, qb = idx & 7;
  const int tid = threadIdx.x, w = tid >> 6, lane = tid & 63, g = lane >> 4, c = lane & 15;
  const int i0 = qb * 128 + w * 32;  // this wave's first q-row
  const ushort_t* qh = q + (size_t)n * 65536;
  const char* khb = (const char*)(k + (size_t)n * 65536);
  const char* vhb = (const char*)(vt + (size_t)n * 65536);
  char* pwb = (char*)&Pb[w][0];

  const int r0 = w * 16 + (lane >> 3);
  const int csw = (((lane & 7) ^ (lane >> 3)) << 4);

#define STAGE_K(buf, jt_)                                                                   \
  do {                                                                                      \
    __builtin_amdgcn_global_load_lds(AS1C(khb + ((size_t)(jt_)*64 + r0) * 128 + csw),       \
                                     AS3(&Kb[buf][(w * 2 + 0) * 512]), 16, 0, 0);           \
    __builtin_amdgcn_global_load_lds(AS1C(khb + ((size_t)(jt_)*64 + r0 + 8) * 128 + csw),   \
                                     AS3(&Kb[buf][(w * 2 + 1) * 512]), 16, 0, 0);           \
  } while (0)
#define STAGE_V(buf, jt_)                                                                   \
  do {                                                                                      \
    __builtin_amdgcn_global_load_lds(AS1C(vhb + (size_t)r0 * 2048 + (jt_)*128 + csw),       \
                                     AS3(&Vb[buf][(w * 2 + 0) * 512]), 16, 0, 0);           \
    __builtin_amdgcn_global_load_lds(AS1C(vhb + (size_t)(r0 + 8) * 2048 + (jt_)*128 + csw), \
                                     AS3(&Vb[buf][(w * 2 + 1) * 512]), 16, 0, 0);           \
  } while (0)
#define KFRAG(buf, jn, h)                                                     \
  (*(const s16x8*)((const char*)&Kb[buf][0] +                                 \
                   (((((jn)*16 + c) * 128 + (h)*64 + g * 16)) ^ ((c & 7) << 4))))
#define VFRAG(buf, dn, ks_)                                                   \
  (*(const s16x8*)((const char*)&Vb[buf][0] +                                 \
                   (((((dn)*16 + c) * 128 + (ks_)*64 + g * 16)) ^ ((c & 7) << 4))))

  // Q fragments + softmax bias for both 16-row fragments
  s16x8 aq[2][2];
  float bias_r[2][4];
#pragma unroll
  for (int fr = 0; fr < 2; ++fr) {
    aq[fr][0] = *(const s16x8*)&qh[(i0 + fr * 16 + c) * 64 + g * 8];
    aq[fr][1] = *(const s16x8*)&qh[(i0 + fr * 16 + c) * 64 + 32 + g * 8];
    const float* sb = stats + (size_t)n * 1024 + i0 + fr * 16;
#pragma unroll
    for (int r = 0; r < 4; ++r) bias_r[fr][r] = sb[4 * g + r];
  }

  f32x4 cacc[2][4] = {};
  float* arow = attn + (size_t)n * 1048576;

  STAGE_K(0, 0);
  STAGE_V(0, 0);
  asm volatile("s_waitcnt vmcnt(0) lgkmcnt(0)" ::: "memory");
  SBAR();
  for (int jt = 0; jt < 16; ++jt) {
    const int cur = jt & 1;
    if (jt < 15) { STAGE_K(cur ^ 1, jt + 1); STAGE_V(cur ^ 1, jt + 1); }
    // QK^T for both fragments
    f32x4 s[2][4];
    __builtin_amdgcn_s_setprio(1);
#pragma unroll
    for (int fr = 0; fr < 2; ++fr)
#pragma unroll
      for (int jn = 0; jn < 4; ++jn) {
        f32x4 z = {0.f, 0.f, 0.f, 0.f};
        z = __builtin_amdgcn_mfma_f32_16x16x32_bf16(aq[fr][0], KFRAG(cur, jn, 0), z, 0, 0, 0);
        z = __builtin_amdgcn_mfma_f32_16x16x32_bf16(aq[fr][1], KFRAG(cur, jn, 1), z, 0, 0, 0);
        s[fr][jn] = z;
      }
    __builtin_amdgcn_s_setprio(0);
    // write P tile (bf16, swizzled): tile row = fr*16 + 4g + r
#pragma unroll
    for (int fr = 0; fr < 2; ++fr)
#pragma unroll
      for (int jn = 0; jn < 4; ++jn)
#pragma unroll
        for (int r = 0; r < 4; ++r) {
          const float p = EXP2F(s[fr][jn][r] - bias_r[fr][r]);
          const int row = fr * 16 + 4 * g + r;
          const int A = (row << 7) + ((jn * 16 + c) << 1);
          *(ushort_t*)(pwb + (A ^ ((row & 7) << 4))) = f2bf(p);
        }
    WAVE_LDS_FENCE();
    // PV for both fragments; V-frag loaded once, used twice
    __builtin_amdgcn_s_setprio(1);
#pragma unroll
    for (int ks = 0; ks < 2; ++ks) {
      s16x8 pa[2];
#pragma unroll
      for (int fr = 0; fr < 2; ++fr) {
        const int A = ((fr * 16 + c) << 7) + (ks << 6) + (g << 4);
        pa[fr] = *(const s16x8*)(pwb + (A ^ ((c & 7) << 4)));
      }
#pragma unroll
      for (int dn = 0; dn < 4; ++dn) {
        const s16x8 bv = VFRAG(cur, dn, ks);
        cacc[0][dn] = __builtin_amdgcn_mfma_f32_16x16x32_bf16(pa[0], bv, cacc[0][dn], 0, 0, 0);
        cacc[1][dn] = __builtin_amdgcn_mfma_f32_16x16x32_bf16(pa[1], bv, cacc[1][dn], 0, 0, 0);
      }
    }
    __builtin_amdgcn_s_setprio(0);
    // coalesced nontemporal f32 stores (8 per lane)
#pragma unroll
    for (int fr = 0; fr < 2; ++fr)
#pragma unroll
      for (int e = 0; e < 4; ++e) {
        const int row = fr * 16 + g + 4 * e;
        const int A = (row << 7) + (c << 3);
        const u16x4 hv = *(const u16x4*)(pwb + (A ^ ((row & 7) << 4)));
        f32x4 fv;
#pragma unroll
        for (int t2 = 0; t2 < 4; ++t2) fv[t2] = bf2f(hv[t2]);
        __builtin_nontemporal_store(
            fv, (f32x4*)&arow[(size_t)(i0 + row) * 1024 + jt * 64 + c * 4]);
      }
    if (jt < 15) {
      // 4 staging loads retired; the 8 P-stores stay in flight
      asm volatile("s_waitcnt vmcnt(8) lgkmcnt(0)" ::: "memory");
      SBAR();
    }
  }

  ushort_t* ch = ctx + (size_t)n * 65536;
#pragma unroll
  for (int fr = 0; fr < 2; ++fr)
#pragma unroll
    for (int dn = 0; dn < 4; ++dn)
#pragma unroll
      for (int r = 0; r < 4; ++r)
        ch[(size_t)(i0 + fr * 16 + 4 * g + r) * 64 + dn * 16 + c] = f2bf(cacc[fr][dn][r]);
#undef STAGE_K
#undef STAGE_V
#undef KFRAG
#undef VFRAG
}

// ---------------- LayerNorm (input x = proj + residual, prefused) ----------------
__global__ __launch_bounds__(256) void ln_kernel(const float* __restrict__ xin,
                                                 const float* __restrict__ gamma,
                                                 const float* __restrict__ beta,
                                                 float* __restrict__ out) {
  __shared__ float sred[4], ssred[4];
  const int row = blockIdx.x, t = threadIdx.x;
  const float4 x = ((const float4*)(xin + (size_t)row * 1024))[t];
  float s = x.x + x.y + x.z + x.w;
  float ss = x.x * x.x + x.y * x.y + x.z * x.z + x.w * x.w;
#pragma unroll
  for (int msk = 1; msk < 64; msk <<= 1) {
    s += __shfl_xor(s, msk);
    ss += __shfl_xor(ss, msk);
  }
  const int w = t >> 6, lane = t & 63;
  if (lane == 0) { sred[w] = s; ssred[w] = ss; }
  __syncthreads();
  s = sred[0] + sred[1] + sred[2] + sred[3];
  ss = ssred[0] + ssred[1] + ssred[2] + ssred[3];
  const float mu = s * (1.f / 1024.f);
  const float var = ss * (1.f / 1024.f) - mu * mu;
  const float rs = rsqrtf(var + 1e-5f);
  const float4 gm = ((const float4*)gamma)[t];
  const float4 bt = ((const float4*)beta)[t];
  float4 o;
  o.x = (x.x - mu) * rs * gm.x + bt.x;
  o.y = (x.y - mu) * rs * gm.y + bt.y;
  o.z = (x.z - mu) * rs * gm.z + bt.z;
  o.w = (x.w - mu) * rs * gm.w + bt.w;
  ((float4*)(out + (size_t)row * 1024))[t] = o;
}

extern "C" void kernel_launch(void* const* d_in, const int* in_sizes, int n_in,
                              void* d_out, int out_size, void* d_ws, size_t ws_size,
                              hipStream_t stream) {
  const float* key   = (const float*)d_in[0];
  const float* value = (const float*)d_in[1];
  const float* query = (const float*)d_in[2];
  const float* Wq = (const float*)d_in[3];  const float* bq = (const float*)d_in[4];
  const float* Wk = (const float*)d_in[5];  const float* bk = (const float*)d_in[6];
  const float* Wv = (const float*)d_in[7];  const float* bv = (const float*)d_in[8];
  const float* Wo = (const float*)d_in[9];  const float* bo = (const float*)d_in[10];
  const float* gamma = (const float*)d_in[11];
  const float* beta  = (const float*)d_in[12];

  char* ws = (char*)d_ws;
  ushort_t* q_   = (ushort_t*)(ws + 0);
  ushort_t* k_   = (ushort_t*)(ws + 16777216);
  ushort_t* vt_  = (ushort_t*)(ws + 33554432);
  ushort_t* ctx_ = (ushort_t*)(ws + 50331648);
  ushort_t* wo_  = (ushort_t*)(ws + 67108864);
  float*    x_   = (float*)(ws + 0);  // aliases q_,k_ (dead after attention)

  char* o8 = (char*)d_out;
  float*    outp  = (float*)o8;
  float*    attnp = (float*)(o8 + 33554432);
  // stats table in the outp region (dead until ln_kernel, OUTSIDE attn's writes)
  float*    stats = (float*)o8;
  // scratch inside the (not-yet-written) attn region:
  ushort_t* xq   = (ushort_t*)(o8 + 33554432);   // query bf16
  ushort_t* xk   = (ushort_t*)(o8 + 50331648);   // key   bf16
  ushort_t* xv   = (ushort_t*)(o8 + 67108864);   // value bf16
  ushort_t* wqkv = (ushort_t*)(o8 + 83886080);   // concat [3072][1024] bf16
  ushort_t* v_   = (ushort_t*)(o8 + 90177536);
  float*    bqkv = (float*)(o8 + 106954752);     // concat bias [3072] f32

  cvt3_kernel<<<dim3(8192, 3), 256, 0, stream>>>(query, key, value, xq);
  cvtw_kernel<<<dim3(1024, 4), 256, 0, stream>>>(Wq, Wk, Wv, Wo, wqkv, wo_);
  biascat_kernel<<<12, 256, 0, stream>>>(bq, bk, bv, bqkv);

  // fused QKV projection: 1536 blocks x 512 threads
  gemm_nt<1, 0><<<dim3(24, 64), 512, 0, stream>>>(xq, xk, xv, wqkv, bqkv, nullptr,
                                                  q_, k_, v_);

  transpose_v<<<dim3(16, 128), 256, 0, stream>>>(v_, vt_);

  stats_kernel<<<512, 256, 0, stream>>>(q_, k_, stats);

  attn_kernel<<<1024, 256, 0, stream>>>(q_, k_, vt_, stats, attnp, ctx_);

  // out-proj with fused residual: x = ctx @ Wo^T + bo + query
  gemm_nt<0, 1><<<dim3(8, 64), 512, 0, stream>>>(ctx_, ctx_, ctx_, wo_, bo, query,
                                                 x_, x_, x_);

  ln_kernel<<<8192, 256, 0, stream>>>(x_, gamma, beta, outp);
}

// Round 14
// 318.408 us; speedup vs baseline: 1.0057x; 1.0057x over previous
//
#include <hip/hip_runtime.h>
#include <stdint.h>

typedef unsigned short ushort_t;
typedef __attribute__((ext_vector_type(8))) short s16x8;
typedef __attribute__((ext_vector_type(8))) unsigned short u16x8;
typedef __attribute__((ext_vector_type(4))) unsigned short u16x4;
typedef __attribute__((ext_vector_type(4))) float f32x4;

#define AS1C(p) ((const __attribute__((address_space(1))) void*)(p))
#define AS3(p)  ((__attribute__((address_space(3))) void*)(p))

// 0.5 (attention scale) * log2(e)  — baked into Wq/bq so softmax can use exp2
#define QSCALE 0.7213475204444817f

// hardware exp2 / log2 (v_exp_f32 = 2^x, v_log_f32 = log2 x)
#define EXP2F(x) __builtin_amdgcn_exp2f(x)
#define LOG2F(x) __builtin_amdgcn_logf(x)

// per-wave LDS fence: own-wave ds op ordering without s_barrier
#define WAVE_LDS_FENCE()                                    \
  do {                                                      \
    asm volatile("s_waitcnt lgkmcnt(0)" ::: "memory");      \
    __builtin_amdgcn_sched_barrier(0);                      \
  } while (0)

// raw workgroup barrier, compiler-fenced on both sides (waits done explicitly)
#define SBAR()                                              \
  do {                                                      \
    __builtin_amdgcn_sched_barrier(0);                      \
    __builtin_amdgcn_s_barrier();                           \
    __builtin_amdgcn_sched_barrier(0);                      \
  } while (0)

__device__ __forceinline__ ushort_t f2bf(float f) {
  uint32_t u = __float_as_uint(f);
  u += 0x7fffu + ((u >> 16) & 1u);
  return (ushort_t)(u >> 16);
}
__device__ __forceinline__ float bf2f(ushort_t h) {
  return __uint_as_float(((uint32_t)h) << 16);
}

// ---------------- activations f32 -> bf16 (3 tensors, one launch) ----------------
__global__ __launch_bounds__(256) void cvt3_kernel(const float* __restrict__ s0,
                                                   const float* __restrict__ s1,
                                                   const float* __restrict__ s2,
                                                   ushort_t* __restrict__ dst) {
  const int y = blockIdx.y;
  const float* src = y == 0 ? s0 : (y == 1 ? s1 : s2);
  const int i = blockIdx.x * 256 + threadIdx.x;
  const float4 v = ((const float4*)src)[i];
  ushort4 o;
  o.x = f2bf(v.x); o.y = f2bf(v.y); o.z = f2bf(v.z); o.w = f2bf(v.w);
  ((ushort4*)(dst + (size_t)y * 8388608))[i] = o;
}

// ---------------- weights f32 -> bf16 (Wq scaled by QSCALE), one launch ----------------
__global__ __launch_bounds__(256) void cvtw_kernel(const float* __restrict__ w0,
                                                   const float* __restrict__ w1,
                                                   const float* __restrict__ w2,
                                                   const float* __restrict__ w3,
                                                   ushort_t* __restrict__ dqkv,
                                                   ushort_t* __restrict__ dwo) {
  const int y = blockIdx.y;
  const float* src = y == 0 ? w0 : (y == 1 ? w1 : (y == 2 ? w2 : w3));
  ushort_t* dst = y < 3 ? dqkv + (size_t)y * 1048576 : dwo;
  const float sc = y == 0 ? QSCALE : 1.0f;
  const int i = blockIdx.x * 256 + threadIdx.x;
  const float4 v = ((const float4*)src)[i];
  ushort4 o;
  o.x = f2bf(v.x * sc); o.y = f2bf(v.y * sc); o.z = f2bf(v.z * sc); o.w = f2bf(v.w * sc);
  ((ushort4*)dst)[i] = o;
}

// ---------------- concat bias (bq scaled) ----------------
__global__ __launch_bounds__(256) void biascat_kernel(const float* __restrict__ bq,
                                                      const float* __restrict__ bk,
                                                      const float* __restrict__ bv,
                                                      float* __restrict__ dst) {
  const int i = blockIdx.x * 256 + threadIdx.x;
  dst[i] = i < 1024 ? bq[i] * QSCALE : (i < 2048 ? bk[i - 1024] : bv[i - 2048]);
}

// ---------------- bf16 NT GEMM, 128x128 tile, BK=32, 3-buffer ring ----------------
// 512 threads / 8 waves (4 M-waves x 2 N-waves; 32x64 per wave, acc[2][4]).
// ADD_RESID: epilogue adds resid[m][n] (residual fused into out-proj).
template <int OUT_BF16, int ADD_RESID>
__global__ __launch_bounds__(512) void gemm_nt(const ushort_t* __restrict__ A0,
                                               const ushort_t* __restrict__ A1,
                                               const ushort_t* __restrict__ A2,
                                               const ushort_t* __restrict__ B,
                                               const float* __restrict__ bias,
                                               const float* __restrict__ resid,
                                               void* __restrict__ C0,
                                               void* __restrict__ C1,
                                               void* __restrict__ C2) {
  __shared__ ushort_t As[3][128 * 32];
  __shared__ ushort_t Bs[3][128 * 32];
  const int tid = threadIdx.x;
  const int w = tid >> 6, lane = tid & 63, g = lane >> 4, c = lane & 15;
  const int wm = w >> 1, wn = w & 1;   // 4 M-waves x 2 N-waves
  const int m0 = blockIdx.y * 128, n0 = blockIdx.x * 128;
  const int sel = n0 >> 10, nloc0 = n0 & 1023;
  const ushort_t* A = sel == 0 ? A0 : (sel == 1 ? A1 : A2);
  char* C = (char*)(sel == 0 ? C0 : (sel == 1 ? C1 : C2));
  f32x4 acc[2][4] = {};

  const int srow = tid >> 2, scol = (tid & 3) << 3;
  const int sdst = (w * 64) * 8;  // wave-uniform base (elems)

#define G_STAGE(buf, k0_)                                                                  \
  do {                                                                                     \
    __builtin_amdgcn_global_load_lds(AS1C(&A[(size_t)(m0 + srow) * 1024 + (k0_) + scol]),  \
                                     AS3(&As[buf][sdst]), 16, 0, 0);                       \
    __builtin_amdgcn_global_load_lds(AS1C(&B[(size_t)(n0 + srow) * 1024 + (k0_) + scol]),  \
                                     AS3(&Bs[buf][sdst]), 16, 0, 0);                       \
  } while (0)

  G_STAGE(0, 0);
  G_STAGE(1, 32);
  asm volatile("s_waitcnt vmcnt(2)" ::: "memory");
  SBAR();
  int cur = 0;
  for (int it = 0; it < 32; ++it) {
    if (it < 30) {
      const int sb = cur >= 1 ? cur - 1 : 2;  // (cur+2)%3
      G_STAGE(sb, 32 * (it + 2));
    }
    s16x8 af[2], bfr[4];
#pragma unroll
    for (int mi = 0; mi < 2; ++mi)
      af[mi] = *(const s16x8*)&As[cur][(wm * 32 + mi * 16 + c) * 32 + g * 8];
#pragma unroll
    for (int ni = 0; ni < 4; ++ni)
      bfr[ni] = *(const s16x8*)&Bs[cur][(wn * 64 + ni * 16 + c) * 32 + g * 8];
    __builtin_amdgcn_s_setprio(1);
#pragma unroll
    for (int mi = 0; mi < 2; ++mi)
#pragma unroll
      for (int ni = 0; ni < 4; ++ni)
        acc[mi][ni] = __builtin_amdgcn_mfma_f32_16x16x32_bf16(af[mi], bfr[ni], acc[mi][ni], 0, 0, 0);
    __builtin_amdgcn_s_setprio(0);
    if (it < 31) {
      if (it < 30)
        asm volatile("s_waitcnt vmcnt(2) lgkmcnt(0)" ::: "memory");
      else
        asm volatile("s_waitcnt vmcnt(0) lgkmcnt(0)" ::: "memory");
      SBAR();
    }
    cur = cur < 2 ? cur + 1 : 0;
  }
#undef G_STAGE

#pragma unroll
  for (int ni = 0; ni < 4; ++ni) {
    const int nn = wn * 64 + ni * 16 + c;
    const float bv = bias[n0 + nn];
#pragma unroll
    for (int mi = 0; mi < 2; ++mi) {
#pragma unroll
      for (int rr = 0; rr < 4; ++rr) {
        const int m = m0 + wm * 32 + mi * 16 + g * 4 + rr;
        float val = acc[mi][ni][rr] + bv;
        if (ADD_RESID) val += resid[(size_t)m * 1024 + nloc0 + nn];
        if (OUT_BF16)
          ((ushort_t*)C)[(size_t)m * 1024 + nloc0 + nn] = f2bf(val);
        else
          ((float*)C)[(size_t)m * 1024 + nloc0 + nn] = val;
      }
    }
  }
}

// ---------------- V transpose per head: vt[n][dh][i] = v[n][i][dh] ----------------
__global__ __launch_bounds__(256) void transpose_v(const ushort_t* __restrict__ v,
                                                   ushort_t* __restrict__ vt) {
  __shared__ ushort_t T[64][72];
  const int n = blockIdx.y, ib = blockIdx.x;
  const int t = threadIdx.x;
  {
    const int row = t >> 2, cb = (t & 3) << 4;
    const ushort_t* src = v + (size_t)n * 65536 + (size_t)(ib * 64 + row) * 64 + cb;
    *(u16x8*)&T[row][cb] = *(const u16x8*)src;
    *(u16x8*)&T[row][cb + 8] = *(const u16x8*)(src + 8);
  }
  __syncthreads();
  {
    const int dh = t >> 2, ibs = (t & 3) << 4;
    u16x8 a, b;
#pragma unroll
    for (int e = 0; e < 8; ++e) { a[e] = T[ibs + e][dh]; b[e] = T[ibs + 8 + e][dh]; }
    ushort_t* dst = vt + (size_t)n * 65536 + (size_t)dh * 1024 + ib * 64 + ibs;
    *(u16x8*)dst = a;
    *(u16x8*)(dst + 8) = b;
  }
}

// ---------------- softmax stats: bias[row] = log2( sum_j exp2(S[row][j]) ) ----------------
// 128 q-rows per block (4 waves x 32 rows, 2 fragments each); 1024 blocks ->
// 4 blocks/CU, 16 waves/CU (R10-proven occupancy). 3-buffer ring, vmcnt(2).
__global__ __launch_bounds__(256) void stats_kernel(const ushort_t* __restrict__ q,
                                                    const ushort_t* __restrict__ k,
                                                    float* __restrict__ bias_out) {
  __shared__ ushort_t Kb[3][64 * 64];
  const int wg = blockIdx.x;
  const int idx = ((wg & 7) << 7) | (wg >> 3);  // XCD swizzle (bijective, 1024=8*128)
  const int n = idx >> 3, qb = idx & 7;
  const int tid = threadIdx.x, w = tid >> 6, lane = tid & 63, g = lane >> 4, c = lane & 15;
  const int q0 = qb * 128 + w * 32;
  const ushort_t* qh = q + (size_t)n * 65536;
  const char* khb = (const char*)(k + (size_t)n * 65536);

  const int r0 = w * 16 + (lane >> 3);
  const int csw = (((lane & 7) ^ (lane >> 3)) << 4);

#define STAGE_KS(buf, jt_)                                                                  \
  do {                                                                                      \
    __builtin_amdgcn_global_load_lds(AS1C(khb + ((size_t)(jt_)*64 + r0) * 128 + csw),       \
                                     AS3(&Kb[buf][(w * 2 + 0) * 512]), 16, 0, 0);           \
    __builtin_amdgcn_global_load_lds(AS1C(khb + ((size_t)(jt_)*64 + r0 + 8) * 128 + csw),   \
                                     AS3(&Kb[buf][(w * 2 + 1) * 512]), 16, 0, 0);           \
  } while (0)
#define KFRAGS(buf, jn, h)                                                    \
  (*(const s16x8*)((const char*)&Kb[buf][0] +                                 \
                   (((((jn)*16 + c) * 128 + (h)*64 + g * 16)) ^ ((c & 7) << 4))))

  s16x8 aq[2][2];
#pragma unroll
  for (int fr = 0; fr < 2; ++fr) {
    aq[fr][0] = *(const s16x8*)&qh[(q0 + fr * 16 + c) * 64 + g * 8];
    aq[fr][1] = *(const s16x8*)&qh[(q0 + fr * 16 + c) * 64 + 32 + g * 8];
  }

  float l_acc[2][4] = {};

  STAGE_KS(0, 0);
  STAGE_KS(1, 1);
  asm volatile("s_waitcnt vmcnt(2)" ::: "memory");
  SBAR();
  int cur = 0;
  for (int jt = 0; jt < 16; ++jt) {
    if (jt < 14) {
      const int sb = cur >= 1 ? cur - 1 : 2;  // (cur+2)%3
      STAGE_KS(sb, jt + 2);
    }
    f32x4 sfr[2][4];
    __builtin_amdgcn_s_setprio(1);
#pragma unroll
    for (int fr = 0; fr < 2; ++fr)
#pragma unroll
      for (int jn = 0; jn < 4; ++jn) {
        f32x4 z = {0.f, 0.f, 0.f, 0.f};
        z = __builtin_amdgcn_mfma_f32_16x16x32_bf16(aq[fr][0], KFRAGS(cur, jn, 0), z, 0, 0, 0);
        z = __builtin_amdgcn_mfma_f32_16x16x32_bf16(aq[fr][1], KFRAGS(cur, jn, 1), z, 0, 0, 0);
        sfr[fr][jn] = z;
      }
    __builtin_amdgcn_s_setprio(0);
#pragma unroll
    for (int fr = 0; fr < 2; ++fr)
#pragma unroll
      for (int rr = 0; rr < 4; ++rr)
        l_acc[fr][rr] += EXP2F(sfr[fr][0][rr]) + EXP2F(sfr[fr][1][rr]) +
                         EXP2F(sfr[fr][2][rr]) + EXP2F(sfr[fr][3][rr]);
    if (jt < 15) {
      if (jt < 14)
        asm volatile("s_waitcnt vmcnt(2) lgkmcnt(0)" ::: "memory");
      else
        asm volatile("s_waitcnt vmcnt(0) lgkmcnt(0)" ::: "memory");
      SBAR();
    }
    cur = cur < 2 ? cur + 1 : 0;
  }

#pragma unroll
  for (int fr = 0; fr < 2; ++fr)
#pragma unroll
    for (int rr = 0; rr < 4; ++rr) {
      float l = l_acc[fr][rr];
      l += __shfl_xor(l, 1);
      l += __shfl_xor(l, 2);
      l += __shfl_xor(l, 4);
      l += __shfl_xor(l, 8);
      if (c == 0)
        bias_out[(size_t)n * 1024 + q0 + fr * 16 + g * 4 + rr] = LOG2F(l);
    }
#undef STAGE_KS
#undef KFRAGS
}

// ---------------- attention: single sweep, 128 q-rows per block (R10 exact) ----------------
__global__ __launch_bounds__(256) void attn_kernel(const ushort_t* __restrict__ q,
                                                   const ushort_t* __restrict__ k,
                                                   const ushort_t* __restrict__ vt,
                                                   const float* __restrict__ stats,
                                                   float* __restrict__ attn,
                                                   ushort_t* __restrict__ ctx) {
  __shared__ ushort_t Kb[2][64 * 64];
  __shared__ ushort_t Vb[2][64 * 64];
  __shared__ ushort_t Pb[4][32 * 64];
  const int wg = blockIdx.x;
  const int idx = ((wg & 7) << 7) | (wg >> 3);  // XCD swizzle (bijective, 1024=8*128)
  const int n = idx >> 3, qb = idx & 7;
  const int tid = threadIdx.x, w = tid >> 6, lane = tid & 63, g = lane >> 4, c = lane & 15;
  const int i0 = qb * 128 + w * 32;  // this wave's first q-row
  const ushort_t* qh = q + (size_t)n * 65536;
  const char* khb = (const char*)(k + (size_t)n * 65536);
  const char* vhb = (const char*)(vt + (size_t)n * 65536);
  char* pwb = (char*)&Pb[w][0];

  const int r0 = w * 16 + (lane >> 3);
  const int csw = (((lane & 7) ^ (lane >> 3)) << 4);

#define STAGE_K(buf, jt_)                                                                   \
  do {                                                                                      \
    __builtin_amdgcn_global_load_lds(AS1C(khb + ((size_t)(jt_)*64 + r0) * 128 + csw),       \
                                     AS3(&Kb[buf][(w * 2 + 0) * 512]), 16, 0, 0);           \
    __builtin_amdgcn_global_load_lds(AS1C(khb + ((size_t)(jt_)*64 + r0 + 8) * 128 + csw),   \
                                     AS3(&Kb[buf][(w * 2 + 1) * 512]), 16, 0, 0);           \
  } while (0)
#define STAGE_V(buf, jt_)                                                                   \
  do {                                                                                      \
    __builtin_amdgcn_global_load_lds(AS1C(vhb + (size_t)r0 * 2048 + (jt_)*128 + csw),       \
                                     AS3(&Vb[buf][(w * 2 + 0) * 512]), 16, 0, 0);           \
    __builtin_amdgcn_global_load_lds(AS1C(vhb + (size_t)(r0 + 8) * 2048 + (jt_)*128 + csw), \
                                     AS3(&Vb[buf][(w * 2 + 1) * 512]), 16, 0, 0);           \
  } while (0)
#define KFRAG(buf, jn, h)                                                     \
  (*(const s16x8*)((const char*)&Kb[buf][0] +                                 \
                   (((((jn)*16 + c) * 128 + (h)*64 + g * 16)) ^ ((c & 7) << 4))))
#define VFRAG(buf, dn, ks_)                                                   \
  (*(const s16x8*)((const char*)&Vb[buf][0] +                                 \
                   (((((dn)*16 + c) * 128 + (ks_)*64 + g * 16)) ^ ((c & 7) << 4))))

  // Q fragments + softmax bias for both 16-row fragments
  s16x8 aq[2][2];
  float bias_r[2][4];
#pragma unroll
  for (int fr = 0; fr < 2; ++fr) {
    aq[fr][0] = *(const s16x8*)&qh[(i0 + fr * 16 + c) * 64 + g * 8];
    aq[fr][1] = *(const s16x8*)&qh[(i0 + fr * 16 + c) * 64 + 32 + g * 8];
    const float* sb = stats + (size_t)n * 1024 + i0 + fr * 16;
#pragma unroll
    for (int r = 0; r < 4; ++r) bias_r[fr][r] = sb[4 * g + r];
  }

  f32x4 cacc[2][4] = {};
  float* arow = attn + (size_t)n * 1048576;

  STAGE_K(0, 0);
  STAGE_V(0, 0);
  asm volatile("s_waitcnt vmcnt(0) lgkmcnt(0)" ::: "memory");
  SBAR();
  for (int jt = 0; jt < 16; ++jt) {
    const int cur = jt & 1;
    if (jt < 15) { STAGE_K(cur ^ 1, jt + 1); STAGE_V(cur ^ 1, jt + 1); }
    // QK^T for both fragments
    f32x4 s[2][4];
    __builtin_amdgcn_s_setprio(1);
#pragma unroll
    for (int fr = 0; fr < 2; ++fr)
#pragma unroll
      for (int jn = 0; jn < 4; ++jn) {
        f32x4 z = {0.f, 0.f, 0.f, 0.f};
        z = __builtin_amdgcn_mfma_f32_16x16x32_bf16(aq[fr][0], KFRAG(cur, jn, 0), z, 0, 0, 0);
        z = __builtin_amdgcn_mfma_f32_16x16x32_bf16(aq[fr][1], KFRAG(cur, jn, 1), z, 0, 0, 0);
        s[fr][jn] = z;
      }
    __builtin_amdgcn_s_setprio(0);
    // write P tile (bf16, swizzled): tile row = fr*16 + 4g + r
#pragma unroll
    for (int fr = 0; fr < 2; ++fr)
#pragma unroll
      for (int jn = 0; jn < 4; ++jn)
#pragma unroll
        for (int r = 0; r < 4; ++r) {
          const float p = EXP2F(s[fr][jn][r] - bias_r[fr][r]);
          const int row = fr * 16 + 4 * g + r;
          const int A = (row << 7) + ((jn * 16 + c) << 1);
          *(ushort_t*)(pwb + (A ^ ((row & 7) << 4))) = f2bf(p);
        }
    WAVE_LDS_FENCE();
    // PV for both fragments; V-frag loaded once, used twice
    __builtin_amdgcn_s_setprio(1);
#pragma unroll
    for (int ks = 0; ks < 2; ++ks) {
      s16x8 pa[2];
#pragma unroll
      for (int fr = 0; fr < 2; ++fr) {
        const int A = ((fr * 16 + c) << 7) + (ks << 6) + (g << 4);
        pa[fr] = *(const s16x8*)(pwb + (A ^ ((c & 7) << 4)));
      }
#pragma unroll
      for (int dn = 0; dn < 4; ++dn) {
        const s16x8 bv = VFRAG(cur, dn, ks);
        cacc[0][dn] = __builtin_amdgcn_mfma_f32_16x16x32_bf16(pa[0], bv, cacc[0][dn], 0, 0, 0);
        cacc[1][dn] = __builtin_amdgcn_mfma_f32_16x16x32_bf16(pa[1], bv, cacc[1][dn], 0, 0, 0);
      }
    }
    __builtin_amdgcn_s_setprio(0);
    // coalesced nontemporal f32 stores (8 per lane)
#pragma unroll
    for (int fr = 0; fr < 2; ++fr)
#pragma unroll
      for (int e = 0; e < 4; ++e) {
        const int row = fr * 16 + g + 4 * e;
        const int A = (row << 7) + (c << 3);
        const u16x4 hv = *(const u16x4*)(pwb + (A ^ ((row & 7) << 4)));
        f32x4 fv;
#pragma unroll
        for (int t2 = 0; t2 < 4; ++t2) fv[t2] = bf2f(hv[t2]);
        __builtin_nontemporal_store(
            fv, (f32x4*)&arow[(size_t)(i0 + row) * 1024 + jt * 64 + c * 4]);
      }
    if (jt < 15) {
      // 4 staging loads retired; the 8 P-stores stay in flight
      asm volatile("s_waitcnt vmcnt(8) lgkmcnt(0)" ::: "memory");
      SBAR();
    }
  }

  ushort_t* ch = ctx + (size_t)n * 65536;
#pragma unroll
  for (int fr = 0; fr < 2; ++fr)
#pragma unroll
    for (int dn = 0; dn < 4; ++dn)
#pragma unroll
      for (int r = 0; r < 4; ++r)
        ch[(size_t)(i0 + fr * 16 + 4 * g + r) * 64 + dn * 16 + c] = f2bf(cacc[fr][dn][r]);
#undef STAGE_K
#undef STAGE_V
#undef KFRAG
#undef VFRAG
}

// ---------------- LayerNorm (input x = proj + residual, prefused) ----------------
__global__ __launch_bounds__(256) void ln_kernel(const float* __restrict__ xin,
                                                 const float* __restrict__ gamma,
                                                 const float* __restrict__ beta,
                                                 float* __restrict__ out) {
  __shared__ float sred[4], ssred[4];
  const int row = blockIdx.x, t = threadIdx.x;
  const float4 x = ((const float4*)(xin + (size_t)row * 1024))[t];
  float s = x.x + x.y + x.z + x.w;
  float ss = x.x * x.x + x.y * x.y + x.z * x.z + x.w * x.w;
#pragma unroll
  for (int msk = 1; msk < 64; msk <<= 1) {
    s += __shfl_xor(s, msk);
    ss += __shfl_xor(ss, msk);
  }
  const int w = t >> 6, lane = t & 63;
  if (lane == 0) { sred[w] = s; ssred[w] = ss; }
  __syncthreads();
  s = sred[0] + sred[1] + sred[2] + sred[3];
  ss = ssred[0] + ssred[1] + ssred[2] + ssred[3];
  const float mu = s * (1.f / 1024.f);
  const float var = ss * (1.f / 1024.f) - mu * mu;
  const float rs = rsqrtf(var + 1e-5f);
  const float4 gm = ((const float4*)gamma)[t];
  const float4 bt = ((const float4*)beta)[t];
  float4 o;
  o.x = (x.x - mu) * rs * gm.x + bt.x;
  o.y = (x.y - mu) * rs * gm.y + bt.y;
  o.z = (x.z - mu) * rs * gm.z + bt.z;
  o.w = (x.w - mu) * rs * gm.w + bt.w;
  ((float4*)(out + (size_t)row * 1024))[t] = o;
}

extern "C" void kernel_launch(void* const* d_in, const int* in_sizes, int n_in,
                              void* d_out, int out_size, void* d_ws, size_t ws_size,
                              hipStream_t stream) {
  const float* key   = (const float*)d_in[0];
  const float* value = (const float*)d_in[1];
  const float* query = (const float*)d_in[2];
  const float* Wq = (const float*)d_in[3];  const float* bq = (const float*)d_in[4];
  const float* Wk = (const float*)d_in[5];  const float* bk = (const float*)d_in[6];
  const float* Wv = (const float*)d_in[7];  const float* bv = (const float*)d_in[8];
  const float* Wo = (const float*)d_in[9];  const float* bo = (const float*)d_in[10];
  const float* gamma = (const float*)d_in[11];
  const float* beta  = (const float*)d_in[12];

  char* ws = (char*)d_ws;
  ushort_t* q_   = (ushort_t*)(ws + 0);
  ushort_t* k_   = (ushort_t*)(ws + 16777216);
  ushort_t* vt_  = (ushort_t*)(ws + 33554432);
  ushort_t* ctx_ = (ushort_t*)(ws + 50331648);
  ushort_t* wo_  = (ushort_t*)(ws + 67108864);
  float*    x_   = (float*)(ws + 0);  // aliases q_,k_ (dead after attention)

  char* o8 = (char*)d_out;
  float*    outp  = (float*)o8;
  float*    attnp = (float*)(o8 + 33554432);
  // stats table in the outp region (dead until ln_kernel, OUTSIDE attn's writes)
  float*    stats = (float*)o8;
  // scratch inside the (not-yet-written) attn region:
  ushort_t* xq   = (ushort_t*)(o8 + 33554432);   // query bf16
  ushort_t* xk   = (ushort_t*)(o8 + 50331648);   // key   bf16
  ushort_t* xv   = (ushort_t*)(o8 + 67108864);   // value bf16
  ushort_t* wqkv = (ushort_t*)(o8 + 83886080);   // concat [3072][1024] bf16
  ushort_t* v_   = (ushort_t*)(o8 + 90177536);
  float*    bqkv = (float*)(o8 + 106954752);     // concat bias [3072] f32

  cvt3_kernel<<<dim3(8192, 3), 256, 0, stream>>>(query, key, value, xq);
  cvtw_kernel<<<dim3(1024, 4), 256, 0, stream>>>(Wq, Wk, Wv, Wo, wqkv, wo_);
  biascat_kernel<<<12, 256, 0, stream>>>(bq, bk, bv, bqkv);

  // fused QKV projection: 1536 blocks x 512 threads
  gemm_nt<1, 0><<<dim3(24, 64), 512, 0, stream>>>(xq, xk, xv, wqkv, bqkv, nullptr,
                                                  q_, k_, v_);

  transpose_v<<<dim3(16, 128), 256, 0, stream>>>(v_, vt_);

  stats_kernel<<<1024, 256, 0, stream>>>(q_, k_, stats);

  attn_kernel<<<1024, 256, 0, stream>>>(q_, k_, vt_, stats, attnp, ctx_);

  // out-proj with fused residual: x = ctx @ Wo^T + bo + query
  gemm_nt<0, 1><<<dim3(8, 64), 512, 0, stream>>>(ctx_, ctx_, ctx_, wo_, bo, query,
                                                 x_, x_, x_);

  ln_kernel<<<8192, 256, 0, stream>>>(x_, gamma, beta, outp);
}

// Round 15
// 313.497 us; speedup vs baseline: 1.0215x; 1.0157x over previous
//
#include <hip/hip_runtime.h>
#include <stdint.h>

typedef unsigned short ushort_t;
typedef __attribute__((ext_vector_type(8))) short s16x8;
typedef __attribute__((ext_vector_type(8))) unsigned short u16x8;
typedef __attribute__((ext_vector_type(4))) unsigned short u16x4;
typedef __attribute__((ext_vector_type(4))) float f32x4;

#define AS1C(p) ((const __attribute__((address_space(1))) void*)(p))
#define AS3(p)  ((__attribute__((address_space(3))) void*)(p))

// 0.5 (attention scale) * log2(e)  — baked into Wq/bq so softmax can use exp2
#define QSCALE 0.7213475204444817f

// hardware exp2 / log2 (v_exp_f32 = 2^x, v_log_f32 = log2 x)
#define EXP2F(x) __builtin_amdgcn_exp2f(x)
#define LOG2F(x) __builtin_amdgcn_logf(x)

// per-wave LDS fence: own-wave ds op ordering without s_barrier
#define WAVE_LDS_FENCE()                                    \
  do {                                                      \
    asm volatile("s_waitcnt lgkmcnt(0)" ::: "memory");      \
    __builtin_amdgcn_sched_barrier(0);                      \
  } while (0)

// raw workgroup barrier, compiler-fenced on both sides (waits done explicitly)
#define SBAR()                                              \
  do {                                                      \
    __builtin_amdgcn_sched_barrier(0);                      \
    __builtin_amdgcn_s_barrier();                           \
    __builtin_amdgcn_sched_barrier(0);                      \
  } while (0)

__device__ __forceinline__ ushort_t f2bf(float f) {
  uint32_t u = __float_as_uint(f);
  u += 0x7fffu + ((u >> 16) & 1u);
  return (ushort_t)(u >> 16);
}
__device__ __forceinline__ float bf2f(ushort_t h) {
  return __uint_as_float(((uint32_t)h) << 16);
}

// ---------------- activations f32 -> bf16 (3 tensors, one launch) ----------------
__global__ __launch_bounds__(256) void cvt3_kernel(const float* __restrict__ s0,
                                                   const float* __restrict__ s1,
                                                   const float* __restrict__ s2,
                                                   ushort_t* __restrict__ dst) {
  const int y = blockIdx.y;
  const float* src = y == 0 ? s0 : (y == 1 ? s1 : s2);
  const int i = blockIdx.x * 256 + threadIdx.x;
  const float4 v = ((const float4*)src)[i];
  ushort4 o;
  o.x = f2bf(v.x); o.y = f2bf(v.y); o.z = f2bf(v.z); o.w = f2bf(v.w);
  ((ushort4*)(dst + (size_t)y * 8388608))[i] = o;
}

// ---------------- weights f32 -> bf16 (Wq scaled by QSCALE), one launch ----------------
__global__ __launch_bounds__(256) void cvtw_kernel(const float* __restrict__ w0,
                                                   const float* __restrict__ w1,
                                                   const float* __restrict__ w2,
                                                   const float* __restrict__ w3,
                                                   ushort_t* __restrict__ dqkv,
                                                   ushort_t* __restrict__ dwo) {
  const int y = blockIdx.y;
  const float* src = y == 0 ? w0 : (y == 1 ? w1 : (y == 2 ? w2 : w3));
  ushort_t* dst = y < 3 ? dqkv + (size_t)y * 1048576 : dwo;
  const float sc = y == 0 ? QSCALE : 1.0f;
  const int i = blockIdx.x * 256 + threadIdx.x;
  const float4 v = ((const float4*)src)[i];
  ushort4 o;
  o.x = f2bf(v.x * sc); o.y = f2bf(v.y * sc); o.z = f2bf(v.z * sc); o.w = f2bf(v.w * sc);
  ((ushort4*)dst)[i] = o;
}

// ---------------- concat bias (bq scaled) ----------------
__global__ __launch_bounds__(256) void biascat_kernel(const float* __restrict__ bq,
                                                      const float* __restrict__ bk,
                                                      const float* __restrict__ bv,
                                                      float* __restrict__ dst) {
  const int i = blockIdx.x * 256 + threadIdx.x;
  dst[i] = i < 1024 ? bq[i] * QSCALE : (i < 2048 ? bk[i - 1024] : bv[i - 2048]);
}

// ---------------- bf16 NT GEMM, 128x128 tile, BK=32, 3-buffer ring ----------------
// 512 threads / 8 waves (4 M-waves x 2 N-waves; 32x64 per wave, acc[2][4]).
template <int OUT_BF16>
__global__ __launch_bounds__(512) void gemm_nt(const ushort_t* __restrict__ A0,
                                               const ushort_t* __restrict__ A1,
                                               const ushort_t* __restrict__ A2,
                                               const ushort_t* __restrict__ B,
                                               const float* __restrict__ bias,
                                               void* __restrict__ C0,
                                               void* __restrict__ C1,
                                               void* __restrict__ C2) {
  __shared__ ushort_t As[3][128 * 32];
  __shared__ ushort_t Bs[3][128 * 32];
  const int tid = threadIdx.x;
  const int w = tid >> 6, lane = tid & 63, g = lane >> 4, c = lane & 15;
  const int wm = w >> 1, wn = w & 1;   // 4 M-waves x 2 N-waves
  const int m0 = blockIdx.y * 128, n0 = blockIdx.x * 128;
  const int sel = n0 >> 10, nloc0 = n0 & 1023;
  const ushort_t* A = sel == 0 ? A0 : (sel == 1 ? A1 : A2);
  char* C = (char*)(sel == 0 ? C0 : (sel == 1 ? C1 : C2));
  f32x4 acc[2][4] = {};

  const int srow = tid >> 2, scol = (tid & 3) << 3;
  const int sdst = (w * 64) * 8;  // wave-uniform base (elems)

#define G_STAGE(buf, k0_)                                                                  \
  do {                                                                                     \
    __builtin_amdgcn_global_load_lds(AS1C(&A[(size_t)(m0 + srow) * 1024 + (k0_) + scol]),  \
                                     AS3(&As[buf][sdst]), 16, 0, 0);                       \
    __builtin_amdgcn_global_load_lds(AS1C(&B[(size_t)(n0 + srow) * 1024 + (k0_) + scol]),  \
                                     AS3(&Bs[buf][sdst]), 16, 0, 0);                       \
  } while (0)

  G_STAGE(0, 0);
  G_STAGE(1, 32);
  asm volatile("s_waitcnt vmcnt(2)" ::: "memory");
  SBAR();
  int cur = 0;
  for (int it = 0; it < 32; ++it) {
    if (it < 30) {
      const int sb = cur >= 1 ? cur - 1 : 2;  // (cur+2)%3
      G_STAGE(sb, 32 * (it + 2));
    }
    s16x8 af[2], bfr[4];
#pragma unroll
    for (int mi = 0; mi < 2; ++mi)
      af[mi] = *(const s16x8*)&As[cur][(wm * 32 + mi * 16 + c) * 32 + g * 8];
#pragma unroll
    for (int ni = 0; ni < 4; ++ni)
      bfr[ni] = *(const s16x8*)&Bs[cur][(wn * 64 + ni * 16 + c) * 32 + g * 8];
    __builtin_amdgcn_s_setprio(1);
#pragma unroll
    for (int mi = 0; mi < 2; ++mi)
#pragma unroll
      for (int ni = 0; ni < 4; ++ni)
        acc[mi][ni] = __builtin_amdgcn_mfma_f32_16x16x32_bf16(af[mi], bfr[ni], acc[mi][ni], 0, 0, 0);
    __builtin_amdgcn_s_setprio(0);
    if (it < 31) {
      if (it < 30)
        asm volatile("s_waitcnt vmcnt(2) lgkmcnt(0)" ::: "memory");
      else
        asm volatile("s_waitcnt vmcnt(0) lgkmcnt(0)" ::: "memory");
      SBAR();
    }
    cur = cur < 2 ? cur + 1 : 0;
  }
#undef G_STAGE

#pragma unroll
  for (int ni = 0; ni < 4; ++ni) {
    const int nn = wn * 64 + ni * 16 + c;
    const float bv = bias[n0 + nn];
#pragma unroll
    for (int mi = 0; mi < 2; ++mi) {
#pragma unroll
      for (int rr = 0; rr < 4; ++rr) {
        const int m = m0 + wm * 32 + mi * 16 + g * 4 + rr;
        const float val = acc[mi][ni][rr] + bv;
        if (OUT_BF16)
          ((ushort_t*)C)[(size_t)m * 1024 + nloc0 + nn] = f2bf(val);
        else
          ((float*)C)[(size_t)m * 1024 + nloc0 + nn] = val;
      }
    }
  }
}

// ---------------- V transpose per head: vt[n][dh][i] = v[n][i][dh] ----------------
__global__ __launch_bounds__(256) void transpose_v(const ushort_t* __restrict__ v,
                                                   ushort_t* __restrict__ vt) {
  __shared__ ushort_t T[64][72];
  const int n = blockIdx.y, ib = blockIdx.x;
  const int t = threadIdx.x;
  {
    const int row = t >> 2, cb = (t & 3) << 4;
    const ushort_t* src = v + (size_t)n * 65536 + (size_t)(ib * 64 + row) * 64 + cb;
    *(u16x8*)&T[row][cb] = *(const u16x8*)src;
    *(u16x8*)&T[row][cb + 8] = *(const u16x8*)(src + 8);
  }
  __syncthreads();
  {
    const int dh = t >> 2, ibs = (t & 3) << 4;
    u16x8 a, b;
#pragma unroll
    for (int e = 0; e < 8; ++e) { a[e] = T[ibs + e][dh]; b[e] = T[ibs + 8 + e][dh]; }
    ushort_t* dst = vt + (size_t)n * 65536 + (size_t)dh * 1024 + ib * 64 + ibs;
    *(u16x8*)dst = a;
    *(u16x8*)(dst + 8) = b;
  }
}

// ---------------- softmax stats: bias[row] = log2( sum_j exp2(S[row][j]) ) ----------------
// 128 q-rows per block (4 waves x 32 rows, 2 fragments each); 1024 blocks ->
// 4 blocks/CU, 16 waves/CU. 3-buffer ring, counted vmcnt(2).
__global__ __launch_bounds__(256) void stats_kernel(const ushort_t* __restrict__ q,
                                                    const ushort_t* __restrict__ k,
                                                    float* __restrict__ bias_out) {
  __shared__ ushort_t Kb[3][64 * 64];
  const int wg = blockIdx.x;
  const int idx = ((wg & 7) << 7) | (wg >> 3);  // XCD swizzle (bijective, 1024=8*128)
  const int n = idx >> 3, qb = idx & 7;
  const int tid = threadIdx.x, w = tid >> 6, lane = tid & 63, g = lane >> 4, c = lane & 15;
  const int q0 = qb * 128 + w * 32;
  const ushort_t* qh = q + (size_t)n * 65536;
  const char* khb = (const char*)(k + (size_t)n * 65536);

  const int r0 = w * 16 + (lane >> 3);
  const int csw = (((lane & 7) ^ (lane >> 3)) << 4);

#define STAGE_KS(buf, jt_)                                                                  \
  do {                                                                                      \
    __builtin_amdgcn_global_load_lds(AS1C(khb + ((size_t)(jt_)*64 + r0) * 128 + csw),       \
                                     AS3(&Kb[buf][(w * 2 + 0) * 512]), 16, 0, 0);           \
    __builtin_amdgcn_global_load_lds(AS1C(khb + ((size_t)(jt_)*64 + r0 + 8) * 128 + csw),   \
                                     AS3(&Kb[buf][(w * 2 + 1) * 512]), 16, 0, 0);           \
  } while (0)
#define KFRAGS(buf, jn, h)                                                    \
  (*(const s16x8*)((const char*)&Kb[buf][0] +                                 \
                   (((((jn)*16 + c) * 128 + (h)*64 + g * 16)) ^ ((c & 7) << 4))))

  s16x8 aq[2][2];
#pragma unroll
  for (int fr = 0; fr < 2; ++fr) {
    aq[fr][0] = *(const s16x8*)&qh[(q0 + fr * 16 + c) * 64 + g * 8];
    aq[fr][1] = *(const s16x8*)&qh[(q0 + fr * 16 + c) * 64 + 32 + g * 8];
  }

  float l_acc[2][4] = {};

  STAGE_KS(0, 0);
  STAGE_KS(1, 1);
  asm volatile("s_waitcnt vmcnt(2)" ::: "memory");
  SBAR();
  int cur = 0;
  for (int jt = 0; jt < 16; ++jt) {
    if (jt < 14) {
      const int sb = cur >= 1 ? cur - 1 : 2;  // (cur+2)%3
      STAGE_KS(sb, jt + 2);
    }
    f32x4 sfr[2][4];
    __builtin_amdgcn_s_setprio(1);
#pragma unroll
    for (int fr = 0; fr < 2; ++fr)
#pragma unroll
      for (int jn = 0; jn < 4; ++jn) {
        f32x4 z = {0.f, 0.f, 0.f, 0.f};
        z = __builtin_amdgcn_mfma_f32_16x16x32_bf16(aq[fr][0], KFRAGS(cur, jn, 0), z, 0, 0, 0);
        z = __builtin_amdgcn_mfma_f32_16x16x32_bf16(aq[fr][1], KFRAGS(cur, jn, 1), z, 0, 0, 0);
        sfr[fr][jn] = z;
      }
    __builtin_amdgcn_s_setprio(0);
#pragma unroll
    for (int fr = 0; fr < 2; ++fr)
#pragma unroll
      for (int rr = 0; rr < 4; ++rr)
        l_acc[fr][rr] += EXP2F(sfr[fr][0][rr]) + EXP2F(sfr[fr][1][rr]) +
                         EXP2F(sfr[fr][2][rr]) + EXP2F(sfr[fr][3][rr]);
    if (jt < 15) {
      if (jt < 14)
        asm volatile("s_waitcnt vmcnt(2) lgkmcnt(0)" ::: "memory");
      else
        asm volatile("s_waitcnt vmcnt(0) lgkmcnt(0)" ::: "memory");
      SBAR();
    }
    cur = cur < 2 ? cur + 1 : 0;
  }

#pragma unroll
  for (int fr = 0; fr < 2; ++fr)
#pragma unroll
    for (int rr = 0; rr < 4; ++rr) {
      float l = l_acc[fr][rr];
      l += __shfl_xor(l, 1);
      l += __shfl_xor(l, 2);
      l += __shfl_xor(l, 4);
      l += __shfl_xor(l, 8);
      if (c == 0)
        bias_out[(size_t)n * 1024 + q0 + fr * 16 + g * 4 + rr] = LOG2F(l);
    }
#undef STAGE_KS
#undef KFRAGS
}

// ---------------- attention: single sweep, 128 q-rows per block ----------------
// 4 waves x 32 rows (2 fragments each): K/V staged once per 128 rows, V-frags
// reused across fragments, barriers halved per row. Nontemporal f32 P stores.
__global__ __launch_bounds__(256) void attn_kernel(const ushort_t* __restrict__ q,
                                                   const ushort_t* __restrict__ k,
                                                   const ushort_t* __restrict__ vt,
                                                   const float* __restrict__ stats,
                                                   float* __restrict__ attn,
                                                   ushort_t* __restrict__ ctx) {
  __shared__ ushort_t Kb[2][64 * 64];
  __shared__ ushort_t Vb[2][64 * 64];
  __shared__ ushort_t Pb[4][32 * 64];
  const int wg = blockIdx.x;
  const int idx = ((wg & 7) << 7) | (wg >> 3);  // XCD swizzle (bijective, 1024=8*128)
  const int n = idx >> 3, qb = idx & 7;
  const int tid = threadIdx.x, w = tid >> 6, lane = tid & 63, g = lane >> 4, c = lane & 15;
  const int i0 = qb * 128 + w * 32;  // this wave's first q-row
  const ushort_t* qh = q + (size_t)n * 65536;
  const char* khb = (const char*)(k + (size_t)n * 65536);
  const char* vhb = (const char*)(vt + (size_t)n * 65536);
  char* pwb = (char*)&Pb[w][0];

  const int r0 = w * 16 + (lane >> 3);
  const int csw = (((lane & 7) ^ (lane >> 3)) << 4);

#define STAGE_K(buf, jt_)                                                                   \
  do {                                                                                      \
    __builtin_amdgcn_global_load_lds(AS1C(khb + ((size_t)(jt_)*64 + r0) * 128 + csw),       \
                                     AS3(&Kb[buf][(w * 2 + 0) * 512]), 16, 0, 0);           \
    __builtin_amdgcn_global_load_lds(AS1C(khb + ((size_t)(jt_)*64 + r0 + 8) * 128 + csw),   \
                                     AS3(&Kb[buf][(w * 2 + 1) * 512]), 16, 0, 0);           \
  } while (0)
#define STAGE_V(buf, jt_)                                                                   \
  do {                                                                                      \
    __builtin_amdgcn_global_load_lds(AS1C(vhb + (size_t)r0 * 2048 + (jt_)*128 + csw),       \
                                     AS3(&Vb[buf][(w * 2 + 0) * 512]), 16, 0, 0);           \
    __builtin_amdgcn_global_load_lds(AS1C(vhb + (size_t)(r0 + 8) * 2048 + (jt_)*128 + csw), \
                                     AS3(&Vb[buf][(w * 2 + 1) * 512]), 16, 0, 0);           \
  } while (0)
#define KFRAG(buf, jn, h)                                                     \
  (*(const s16x8*)((const char*)&Kb[buf][0] +                                 \
                   (((((jn)*16 + c) * 128 + (h)*64 + g * 16)) ^ ((c & 7) << 4))))
#define VFRAG(buf, dn, ks_)                                                   \
  (*(const s16x8*)((const char*)&Vb[buf][0] +                                 \
                   (((((dn)*16 + c) * 128 + (ks_)*64 + g * 16)) ^ ((c & 7) << 4))))

  // Q fragments + softmax bias for both 16-row fragments
  s16x8 aq[2][2];
  float bias_r[2][4];
#pragma unroll
  for (int fr = 0; fr < 2; ++fr) {
    aq[fr][0] = *(const s16x8*)&qh[(i0 + fr * 16 + c) * 64 + g * 8];
    aq[fr][1] = *(const s16x8*)&qh[(i0 + fr * 16 + c) * 64 + 32 + g * 8];
    const float* sb = stats + (size_t)n * 1024 + i0 + fr * 16;
#pragma unroll
    for (int r = 0; r < 4; ++r) bias_r[fr][r] = sb[4 * g + r];
  }

  f32x4 cacc[2][4] = {};
  float* arow = attn + (size_t)n * 1048576;

  STAGE_K(0, 0);
  STAGE_V(0, 0);
  asm volatile("s_waitcnt vmcnt(0) lgkmcnt(0)" ::: "memory");
  SBAR();
  for (int jt = 0; jt < 16; ++jt) {
    const int cur = jt & 1;
    if (jt < 15) { STAGE_K(cur ^ 1, jt + 1); STAGE_V(cur ^ 1, jt + 1); }
    // QK^T for both fragments
    f32x4 s[2][4];
    __builtin_amdgcn_s_setprio(1);
#pragma unroll
    for (int fr = 0; fr < 2; ++fr)
#pragma unroll
      for (int jn = 0; jn < 4; ++jn) {
        f32x4 z = {0.f, 0.f, 0.f, 0.f};
        z = __builtin_amdgcn_mfma_f32_16x16x32_bf16(aq[fr][0], KFRAG(cur, jn, 0), z, 0, 0, 0);
        z = __builtin_amdgcn_mfma_f32_16x16x32_bf16(aq[fr][1], KFRAG(cur, jn, 1), z, 0, 0, 0);
        s[fr][jn] = z;
      }
    __builtin_amdgcn_s_setprio(0);
    // write P tile (bf16, swizzled): tile row = fr*16 + 4g + r
#pragma unroll
    for (int fr = 0; fr < 2; ++fr)
#pragma unroll
      for (int jn = 0; jn < 4; ++jn)
#pragma unroll
        for (int r = 0; r < 4; ++r) {
          const float p = EXP2F(s[fr][jn][r] - bias_r[fr][r]);
          const int row = fr * 16 + 4 * g + r;
          const int A = (row << 7) + ((jn * 16 + c) << 1);
          *(ushort_t*)(pwb + (A ^ ((row & 7) << 4))) = f2bf(p);
        }
    WAVE_LDS_FENCE();
    // PV for both fragments; V-frag loaded once, used twice
    __builtin_amdgcn_s_setprio(1);
#pragma unroll
    for (int ks = 0; ks < 2; ++ks) {
      s16x8 pa[2];
#pragma unroll
      for (int fr = 0; fr < 2; ++fr) {
        const int A = ((fr * 16 + c) << 7) + (ks << 6) + (g << 4);
        pa[fr] = *(const s16x8*)(pwb + (A ^ ((c & 7) << 4)));
      }
#pragma unroll
      for (int dn = 0; dn < 4; ++dn) {
        const s16x8 bv = VFRAG(cur, dn, ks);
        cacc[0][dn] = __builtin_amdgcn_mfma_f32_16x16x32_bf16(pa[0], bv, cacc[0][dn], 0, 0, 0);
        cacc[1][dn] = __builtin_amdgcn_mfma_f32_16x16x32_bf16(pa[1], bv, cacc[1][dn], 0, 0, 0);
      }
    }
    __builtin_amdgcn_s_setprio(0);
    // coalesced nontemporal f32 stores (8 per lane)
#pragma unroll
    for (int fr = 0; fr < 2; ++fr)
#pragma unroll
      for (int e = 0; e < 4; ++e) {
        const int row = fr * 16 + g + 4 * e;
        const int A = (row << 7) + (c << 3);
        const u16x4 hv = *(const u16x4*)(pwb + (A ^ ((row & 7) << 4)));
        f32x4 fv;
#pragma unroll
        for (int t2 = 0; t2 < 4; ++t2) fv[t2] = bf2f(hv[t2]);
        __builtin_nontemporal_store(
            fv, (f32x4*)&arow[(size_t)(i0 + row) * 1024 + jt * 64 + c * 4]);
      }
    if (jt < 15) {
      // 4 staging loads retired; the 8 P-stores stay in flight
      asm volatile("s_waitcnt vmcnt(8) lgkmcnt(0)" ::: "memory");
      SBAR();
    }
  }

  ushort_t* ch = ctx + (size_t)n * 65536;
#pragma unroll
  for (int fr = 0; fr < 2; ++fr)
#pragma unroll
    for (int dn = 0; dn < 4; ++dn)
#pragma unroll
      for (int r = 0; r < 4; ++r)
        ch[(size_t)(i0 + fr * 16 + 4 * g + r) * 64 + dn * 16 + c] = f2bf(cacc[fr][dn][r]);
#undef STAGE_K
#undef STAGE_V
#undef KFRAG
#undef VFRAG
}

// ---------------- residual + LayerNorm ----------------
__global__ __launch_bounds__(256) void ln_kernel(const float* __restrict__ proj,
                                                 const float* __restrict__ resid,
                                                 const float* __restrict__ gamma,
                                                 const float* __restrict__ beta,
                                                 float* __restrict__ out) {
  __shared__ float sred[4], ssred[4];
  const int row = blockIdx.x, t = threadIdx.x;
  const float4 pv = ((const float4*)(proj + (size_t)row * 1024))[t];
  const float4 rv = ((const float4*)(resid + (size_t)row * 1024))[t];
  float4 x;
  x.x = pv.x + rv.x; x.y = pv.y + rv.y; x.z = pv.z + rv.z; x.w = pv.w + rv.w;
  float s = x.x + x.y + x.z + x.w;
  float ss = x.x * x.x + x.y * x.y + x.z * x.z + x.w * x.w;
#pragma unroll
  for (int msk = 1; msk < 64; msk <<= 1) {
    s += __shfl_xor(s, msk);
    ss += __shfl_xor(ss, msk);
  }
  const int w = t >> 6, lane = t & 63;
  if (lane == 0) { sred[w] = s; ssred[w] = ss; }
  __syncthreads();
  s = sred[0] + sred[1] + sred[2] + sred[3];
  ss = ssred[0] + ssred[1] + ssred[2] + ssred[3];
  const float mu = s * (1.f / 1024.f);
  const float var = ss * (1.f / 1024.f) - mu * mu;
  const float rs = rsqrtf(var + 1e-5f);
  const float4 gm = ((const float4*)gamma)[t];
  const float4 bt = ((const float4*)beta)[t];
  float4 o;
  o.x = (x.x - mu) * rs * gm.x + bt.x;
  o.y = (x.y - mu) * rs * gm.y + bt.y;
  o.z = (x.z - mu) * rs * gm.z + bt.z;
  o.w = (x.w - mu) * rs * gm.w + bt.w;
  ((float4*)(out + (size_t)row * 1024))[t] = o;
}

extern "C" void kernel_launch(void* const* d_in, const int* in_sizes, int n_in,
                              void* d_out, int out_size, void* d_ws, size_t ws_size,
                              hipStream_t stream) {
  const float* key   = (const float*)d_in[0];
  const float* value = (const float*)d_in[1];
  const float* query = (const float*)d_in[2];
  const float* Wq = (const float*)d_in[3];  const float* bq = (const float*)d_in[4];
  const float* Wk = (const float*)d_in[5];  const float* bk = (const float*)d_in[6];
  const float* Wv = (const float*)d_in[7];  const float* bv = (const float*)d_in[8];
  const float* Wo = (const float*)d_in[9];  const float* bo = (const float*)d_in[10];
  const float* gamma = (const float*)d_in[11];
  const float* beta  = (const float*)d_in[12];

  char* ws = (char*)d_ws;
  ushort_t* q_   = (ushort_t*)(ws + 0);
  ushort_t* k_   = (ushort_t*)(ws + 16777216);
  ushort_t* vt_  = (ushort_t*)(ws + 33554432);
  ushort_t* ctx_ = (ushort_t*)(ws + 50331648);
  ushort_t* wo_  = (ushort_t*)(ws + 67108864);
  float*    proj_ = (float*)(ws + 0);  // aliases q_,k_ (dead after attention)

  char* o8 = (char*)d_out;
  float*    outp  = (float*)o8;
  float*    attnp = (float*)(o8 + 33554432);
  // stats table in the outp region (dead until ln_kernel, OUTSIDE attn's writes)
  float*    stats = (float*)o8;
  // scratch inside the (not-yet-written) attn region:
  ushort_t* xq   = (ushort_t*)(o8 + 33554432);   // query bf16
  ushort_t* xk   = (ushort_t*)(o8 + 50331648);   // key   bf16
  ushort_t* xv   = (ushort_t*)(o8 + 67108864);   // value bf16
  ushort_t* wqkv = (ushort_t*)(o8 + 83886080);   // concat [3072][1024] bf16
  ushort_t* v_   = (ushort_t*)(o8 + 90177536);
  float*    bqkv = (float*)(o8 + 106954752);     // concat bias [3072] f32

  cvt3_kernel<<<dim3(8192, 3), 256, 0, stream>>>(query, key, value, xq);
  cvtw_kernel<<<dim3(1024, 4), 256, 0, stream>>>(Wq, Wk, Wv, Wo, wqkv, wo_);
  biascat_kernel<<<12, 256, 0, stream>>>(bq, bk, bv, bqkv);

  // fused QKV projection: 1536 blocks x 512 threads
  gemm_nt<1><<<dim3(24, 64), 512, 0, stream>>>(xq, xk, xv, wqkv, bqkv, q_, k_, v_);

  transpose_v<<<dim3(16, 128), 256, 0, stream>>>(v_, vt_);

  stats_kernel<<<1024, 256, 0, stream>>>(q_, k_, stats);

  attn_kernel<<<1024, 256, 0, stream>>>(q_, k_, vt_, stats, attnp, ctx_);

  gemm_nt<0><<<dim3(8, 64), 512, 0, stream>>>(ctx_, ctx_, ctx_, wo_, bo, proj_, proj_, proj_);

  ln_kernel<<<8192, 256, 0, stream>>>(proj_, query, gamma, beta, outp);
}